// Round 4
// baseline (471.157 us; speedup 1.0000x reference)
//
#include <hip/hip_runtime.h>

#define BB 4
#define CC 1024
#define TT 1024
#define HH 16
#define DD 64

typedef __bf16 v8bf __attribute__((ext_vector_type(8)));
typedef __bf16 v4bf __attribute__((ext_vector_type(4)));
typedef float  v4f  __attribute__((ext_vector_type(4)));

// async global->LDS, 16B per lane; LDS dest = wave-uniform base + lane*16
__device__ __forceinline__ void gl_lds16(const __bf16* g, __bf16* l) {
  __builtin_amdgcn_global_load_lds(
      (const __attribute__((address_space(1))) void*)g,
      (__attribute__((address_space(3))) void*)l, 16, 0, 0);
}

// ---------------- prep: mask expand (block 0) + weight casts ----------------
__global__ __launch_bounds__(256) void prep(
    const void* mraw, float* __restrict__ maskf,
    const float* __restrict__ w_kvq, const float* __restrict__ w_out,
    __bf16* __restrict__ wkb, __bf16* __restrict__ wob)
{
  if (blockIdx.x == 0) {
    __shared__ int flagA, flagB;
    if (threadIdx.x == 0) { flagA = 0; flagB = 0; }
    __syncthreads();
    const unsigned char* mb = (const unsigned char*)mraw;
    const int n = BB * TT;
    int a = 0, bfl = 0;
    for (int i = threadIdx.x; i < n; i += 256) {
      if (mb[i]) { if ((i & 3) == 0) a = 1; else bfl = 1; }
    }
    if (a)   atomicOr(&flagA, 1);
    if (bfl) atomicOr(&flagB, 1);
    __syncthreads();
    int layout;                         // 0=int32, 1=float32, 2=uint8
    if (flagA && !flagB)      layout = 0;
    else if (!flagA && flagB) layout = 1;
    else                      layout = 2;
    for (int i = threadIdx.x; i < n; i += 256) {
      float m;
      if (layout == 0)      m = (((const int*)mraw)[i]   != 0)   ? 1.f : 0.f;
      else if (layout == 1) m = (((const float*)mraw)[i] != 0.f) ? 1.f : 0.f;
      else                  m = (mb[i] != 0)                     ? 1.f : 0.f;
      maskf[i] = m;
    }
    return;
  }
  long i = ((long)blockIdx.x - 1) * 2048 + threadIdx.x * 8;
  const float* src;
  __bf16* dst;
  if (i < (long)3 * CC * CC) { src = w_kvq + i; dst = wkb + i; }
  else { long j = i - (long)3 * CC * CC; src = w_out + j; dst = wob + j; }
  float4 f0 = *(const float4*)src;
  float4 f1 = *(const float4*)(src + 4);
  v8bf o;
  o[0] = (__bf16)f0.x; o[1] = (__bf16)f0.y; o[2] = (__bf16)f0.z; o[3] = (__bf16)f0.w;
  o[4] = (__bf16)f1.x; o[5] = (__bf16)f1.y; o[6] = (__bf16)f1.z; o[7] = (__bf16)f1.w;
  *(v8bf*)dst = o;
}

// ---------------- x [b][c][t] fp32 -> xT [b][t][c] bf16 --------------------
__global__ __launch_bounds__(256) void transpose_x(const float* __restrict__ x,
                                                   __bf16* __restrict__ xT) {
  const int b = blockIdx.z;
  const int t0 = blockIdx.x * 64, c0 = blockIdx.y * 64;
  __shared__ __bf16 T[64][72];
  const int tid = threadIdx.x;
  {
    int row = tid >> 2, coff = (tid & 3) * 16;
    const float* src = x + ((long)b * CC + c0 + row) * TT + t0 + coff;
#pragma unroll
    for (int s = 0; s < 4; s++) {
      float4 f = *(const float4*)(src + s * 4);
      T[row][coff + s * 4 + 0] = (__bf16)f.x;
      T[row][coff + s * 4 + 1] = (__bf16)f.y;
      T[row][coff + s * 4 + 2] = (__bf16)f.z;
      T[row][coff + s * 4 + 3] = (__bf16)f.w;
    }
  }
  __syncthreads();
  {
    int trow = tid >> 2, ccoff = (tid & 3) * 16;
    __bf16 vals[16];
#pragma unroll
    for (int i = 0; i < 16; i++) vals[i] = T[ccoff + i][trow];
    __bf16* dst = xT + ((long)b * TT + t0 + trow) * CC + c0 + ccoff;
    *(v8bf*)dst       = *(v8bf*)&vals[0];
    *(v8bf*)(dst + 8) = *(v8bf*)&vals[8];
  }
}

// ------- MFMA GEMM: C[m][n] = sum_k A[m][k]*BT[n][k]  (K=1024 fixed) -------
// MODE 0 (kvq): k/q thirds -> kqT[t][2C] (LDS-transposed), v third -> vbuf[c][t]
// MODE 1 (out): fp32 out = acc + S
template <int MODE>
__global__ __launch_bounds__(256) void gemm_bt(
    const __bf16* __restrict__ A, const __bf16* __restrict__ BTfull,
    const float* __restrict__ Sfull, float* __restrict__ Ofull,
    __bf16* __restrict__ kqT, __bf16* __restrict__ vbuf,
    long strideBT)
{
  const int bz = blockIdx.z;
  const __bf16* BT = BTfull + (long)bz * strideBT;
  const int m0 = blockIdx.y * 128, n0 = blockIdx.x * 128;
  __shared__ __align__(16) char smem[(MODE == 0) ? 34816 : 16384];
  __bf16 (*As)[32] = (__bf16(*)[32])smem;            // 8 KB
  __bf16 (*Bs)[32] = (__bf16(*)[32])(smem + 8192);   // 8 KB
  const int tid = threadIdx.x;
  const int lane = tid & 63, wave = tid >> 6;
  const int wm = wave >> 1, wn = wave & 1;
  const int ln = lane & 15, q = lane >> 4;

  v4f acc[4][4];
#pragma unroll
  for (int i = 0; i < 4; i++)
#pragma unroll
    for (int j = 0; j < 4; j++) acc[i][j] = (v4f)(0.f);

  const int lr = lane >> 2;          // row within 16-row chunk
  const int lc = (lane & 3) * 8;     // col element within 32
  for (int k0 = 0; k0 < CC; k0 += 32) {
#pragma unroll
    for (int s = 0; s < 2; s++) {
      int row = wave * 32 + s * 16;
      gl_lds16(A  + (long)(m0 + row + lr) * CC + k0 + lc, &As[row][0]);
      gl_lds16(BT + (long)(n0 + row + lr) * CC + k0 + lc, &Bs[row][0]);
    }
    __syncthreads();
    v8bf af[4], bf[4];
#pragma unroll
    for (int mi = 0; mi < 4; mi++) af[mi] = *(v8bf*)&As[wm * 64 + mi * 16 + ln][q * 8];
#pragma unroll
    for (int ni = 0; ni < 4; ni++) bf[ni] = *(v8bf*)&Bs[wn * 64 + ni * 16 + ln][q * 8];
#pragma unroll
    for (int mi = 0; mi < 4; mi++)
#pragma unroll
      for (int ni = 0; ni < 4; ni++)
        acc[mi][ni] = __builtin_amdgcn_mfma_f32_16x16x32_bf16(af[mi], bf[ni], acc[mi][ni], 0, 0, 0);
    __syncthreads();
  }

  if (MODE == 1) {
#pragma unroll
    for (int mi = 0; mi < 4; mi++)
#pragma unroll
      for (int ni = 0; ni < 4; ni++)
#pragma unroll
        for (int r = 0; r < 4; r++) {
          long off = (long)bz * CC * TT + (long)(m0 + wm * 64 + mi * 16 + q * 4 + r) * TT
                   + n0 + wn * 64 + ni * 16 + ln;
          Ofull[off] = acc[mi][ni][r] + Sfull[off];
        }
  } else {
    const int third = m0 >> 10;                      // 0=k, 1=v, 2=q
    if (third == 1) {
      const int mb = m0 - 1024;
#pragma unroll
      for (int mi = 0; mi < 4; mi++)
#pragma unroll
        for (int ni = 0; ni < 4; ni++)
#pragma unroll
          for (int r = 0; r < 4; r++)
            vbuf[((long)bz * CC + mb + wm * 64 + mi * 16 + q * 4 + r) * TT
                 + n0 + wn * 64 + ni * 16 + ln] = (__bf16)acc[mi][ni][r];
    } else {
      __bf16 (*Tl)[136] = (__bf16(*)[136])smem;      // 128x136 bf16 = 34 KB
#pragma unroll
      for (int mi = 0; mi < 4; mi++)
#pragma unroll
        for (int ni = 0; ni < 4; ni++) {
          v4bf pb;
#pragma unroll
          for (int r = 0; r < 4; r++) pb[r] = (__bf16)acc[mi][ni][r];
          *(v4bf*)&Tl[wn * 64 + ni * 16 + ln][wm * 64 + mi * 16 + q * 4] = pb;
        }
      __syncthreads();
      const int dstbase = (third == 0) ? 0 : CC;
      const int mcol = (third == 0) ? m0 : (m0 - 2048);
      int t = tid >> 1, c0 = (tid & 1) * 64;
      __bf16* drow = kqT + ((long)bz * TT + n0 + t) * (2 * CC) + dstbase + mcol + c0;
#pragma unroll
      for (int s = 0; s < 8; s++)
        *(v8bf*)(drow + s * 8) = *(v8bf*)&Tl[t][c0 + s * 8];
    }
  }
}

// ------- fused stats: online (max, sumexp) over all keys -> fstats ---------
// Logit MFMA chain is bit-identical to gemm_pv's recompute.
__global__ __launch_bounds__(256) void attn_fstats(
    const __bf16* __restrict__ kqT, const float* __restrict__ maskf,
    float2* __restrict__ fstats)
{
  const int z = blockIdx.y, h = z >> 2, b = z & 3;
  const int j0 = blockIdx.x * 64;
  const __bf16* kbase = kqT + (long)b * TT * (2 * CC);
  const int tid = threadIdx.x;
  const int lane = tid & 63, wave = tid >> 6;
  const int ln = lane & 15, q = lane >> 4;
  __shared__ float2 red[4][64];

  v8bf bq[4][2];
#pragma unroll
  for (int ni = 0; ni < 4; ni++)
#pragma unroll
    for (int kd = 0; kd < 2; kd++)
      bq[ni][kd] = *(const v8bf*)(kbase + (long)(j0 + ni * 16 + ln) * (2 * CC)
                                  + CC + h * DD + kd * 32 + q * 8);

  float rm[4], rs[4];
#pragma unroll
  for (int ni = 0; ni < 4; ni++) { rm[ni] = -3.4e38f; rs[ni] = 0.f; }

  for (int it = 0; it < 4; it++) {
    const int ibase = wave * 256 + it * 64;
    float4 km4[4];
    v8bf ak[4][2];
#pragma unroll
    for (int mi = 0; mi < 4; mi++) {
      km4[mi] = *(const float4*)(maskf + b * TT + ibase + mi * 16 + q * 4);
#pragma unroll
      for (int kd = 0; kd < 2; kd++)
        ak[mi][kd] = *(const v8bf*)(kbase + (long)(ibase + mi * 16 + ln) * (2 * CC)
                                    + h * DD + kd * 32 + q * 8);
    }
#pragma unroll
    for (int ni = 0; ni < 4; ni++) {
      float lv[16];
      float cm = -3.4e38f;
#pragma unroll
      for (int mi = 0; mi < 4; mi++) {
        v4f l4 = (v4f)(0.f);
        l4 = __builtin_amdgcn_mfma_f32_16x16x32_bf16(ak[mi][0], bq[ni][0], l4, 0, 0, 0);
        l4 = __builtin_amdgcn_mfma_f32_16x16x32_bf16(ak[mi][1], bq[ni][1], l4, 0, 0, 0);
#pragma unroll
        for (int r = 0; r < 4; r++) {
          float km = (r == 0) ? km4[mi].x : (r == 1) ? km4[mi].y : (r == 2) ? km4[mi].z : km4[mi].w;
          float l = (km != 0.f) ? -1e30f : l4[r] * 0.125f;
          lv[mi * 4 + r] = l;
          cm = fmaxf(cm, l);
        }
      }
      float nm = fmaxf(rm[ni], cm);
      float s = 0.f;
#pragma unroll
      for (int i = 0; i < 16; i++) s += __expf(lv[i] - nm);
      rs[ni] = rs[ni] * __expf(rm[ni] - nm) + s;
      rm[ni] = nm;
    }
  }

  // reduce across row-quads (i-splits within wave)
#pragma unroll
  for (int ni = 0; ni < 4; ni++) {
    float m = rm[ni], s = rs[ni];
#pragma unroll
    for (int off = 16; off <= 32; off <<= 1) {
      float om = __shfl_xor(m, off, 64);
      float os = __shfl_xor(s, off, 64);
      float M = fmaxf(m, om);
      s = s * __expf(m - M) + os * __expf(om - M);
      m = M;
    }
    if (q == 0) red[wave][ni * 16 + ln] = make_float2(m, s);
  }
  __syncthreads();
  if (tid < 64) {
    float M = -3.4e38f;
    float2 v[4];
#pragma unroll
    for (int w = 0; w < 4; w++) { v[w] = red[w][tid]; M = fmaxf(M, v[w].x); }
    float S = 0.f;
#pragma unroll
    for (int w = 0; w < 4; w++) S += v[w].y * __expf(v[w].x - M);
    const float qz = (maskf[b * TT + j0 + tid] != 0.f) ? 0.f : 1.f;
    fstats[(long)z * TT + j0 + tid] = make_float2(M, qz / S);
  }
}

// ------- recompute logits, p=exp(l-M)*qz/S -> att; o^T = p^T v^T -----------
__global__ __launch_bounds__(256) void gemm_pv(
    const __bf16* __restrict__ kqT, const __bf16* __restrict__ vbuf,
    const float2* __restrict__ fstats, const float* __restrict__ maskf,
    float* __restrict__ att, __bf16* __restrict__ oT)
{
  const int z = blockIdx.y, h = z >> 2, b = z & 3;
  const int j0 = blockIdx.x * 64;
  __shared__ __align__(16) char smem[50176];
  __bf16 (*Qs)[72] = (__bf16(*)[72])smem;                        // 64*72*2 = 9216
  float* km = (float*)(smem + 9216 + 4 * 9216);                  // 4096
  const int tid = threadIdx.x;
  const int lane = tid & 63, wave = tid >> 6;
  const int ln = lane & 15, q = lane >> 4;
  __bf16 (*Pt)[72] = (__bf16(*)[72])(smem + 9216 + wave * 9216); // per-wave 64x72

  const __bf16* kbase = kqT + (long)b * TT * (2 * CC);
  const __bf16* vbase = vbuf + ((long)b * CC + h * DD) * TT;

#pragma unroll
  for (int s = 0; s < 2; s++) {
    int c = tid + s * 256;
    int row = c >> 3, off = (c & 7) * 8;
    *(v8bf*)&Qs[row][off] = *(const v8bf*)(kbase + (long)(j0 + row) * (2 * CC) + CC + h * DD + off);
  }
  {
    float4 f = *(const float4*)(maskf + b * TT + tid * 4);
    *(float4*)&km[tid * 4] = f;
  }
  __syncthreads();

  v8bf bq[4][2];
#pragma unroll
  for (int ni = 0; ni < 4; ni++)
#pragma unroll
    for (int kd = 0; kd < 2; kd++)
      bq[ni][kd] = *(v8bf*)&Qs[ni * 16 + ln][kd * 32 + q * 8];
  float2 st[4];
#pragma unroll
  for (int ni = 0; ni < 4; ni++) st[ni] = fstats[(long)z * TT + j0 + ni * 16 + ln];

  v4f acc[4][4];
#pragma unroll
  for (int i = 0; i < 4; i++)
#pragma unroll
    for (int j = 0; j < 4; j++) acc[i][j] = (v4f)(0.f);

  for (int it = 0; it < 4; it++) {
    const int ibase = wave * 256 + it * 64;
#pragma unroll
    for (int mi = 0; mi < 4; mi++) {
      const __bf16* arow = kbase + (long)(ibase + mi * 16 + ln) * (2 * CC) + h * DD;
      v8bf ak0 = *(const v8bf*)(arow + q * 8);
      v8bf ak1 = *(const v8bf*)(arow + 32 + q * 8);
#pragma unroll
      for (int ni = 0; ni < 4; ni++) {
        v4f l4 = (v4f)(0.f);
        l4 = __builtin_amdgcn_mfma_f32_16x16x32_bf16(ak0, bq[ni][0], l4, 0, 0, 0);
        l4 = __builtin_amdgcn_mfma_f32_16x16x32_bf16(ak1, bq[ni][1], l4, 0, 0, 0);
        v4bf pb;
#pragma unroll
        for (int r = 0; r < 4; r++) {
          int i_loc = mi * 16 + q * 4 + r;
          int i_glob = ibase + i_loc;
          float l = (km[i_glob] != 0.f) ? -1e30f : l4[r] * 0.125f;
          float p = __expf(l - st[ni].x) * st[ni].y;
          att[((long)z << 20) + (long)i_glob * TT + j0 + ni * 16 + ln] = p;
          pb[r] = (__bf16)p;
        }
        *(v4bf*)&Pt[ni * 16 + ln][mi * 16 + q * 4] = pb;
      }
    }
    v8bf ap[4][2], bv[4][2];
#pragma unroll
    for (int ji = 0; ji < 4; ji++)
#pragma unroll
      for (int ki = 0; ki < 2; ki++)
        ap[ji][ki] = *(v8bf*)&Pt[ji * 16 + ln][ki * 32 + q * 8];
#pragma unroll
    for (int di = 0; di < 4; di++)
#pragma unroll
      for (int ki = 0; ki < 2; ki++)
        bv[di][ki] = *(const v8bf*)(vbase + (long)(di * 16 + ln) * TT + ibase + ki * 32 + q * 8);
#pragma unroll
    for (int ji = 0; ji < 4; ji++)
#pragma unroll
      for (int di = 0; di < 4; di++) {
        acc[ji][di] = __builtin_amdgcn_mfma_f32_16x16x32_bf16(ap[ji][0], bv[di][0], acc[ji][di], 0, 0, 0);
        acc[ji][di] = __builtin_amdgcn_mfma_f32_16x16x32_bf16(ap[ji][1], bv[di][1], acc[ji][di], 0, 0, 0);
      }
  }

  float (*red)[68] = (float(*)[68])(smem + 9216);
  for (int w = 0; w < 4; w++) {
    __syncthreads();
    if (wave == w) {
#pragma unroll
      for (int ji = 0; ji < 4; ji++)
#pragma unroll
        for (int di = 0; di < 4; di++)
#pragma unroll
          for (int r = 0; r < 4; r++) {
            int row = ji * 16 + q * 4 + r;
            int col = di * 16 + ln;
            if (w == 0) red[row][col] = acc[ji][di][r];
            else        red[row][col] += acc[ji][di][r];
          }
    }
  }
  __syncthreads();
  {
    int row = tid >> 2, c0 = (tid & 3) * 16;
    __bf16 ob[16];
#pragma unroll
    for (int i = 0; i < 16; i++) ob[i] = (__bf16)red[row][c0 + i];
    __bf16* dst = oT + ((long)b * TT + j0 + row) * CC + h * DD + c0;
    *(v8bf*)dst       = *(v8bf*)&ob[0];
    *(v8bf*)(dst + 8) = *(v8bf*)&ob[8];
  }
}

extern "C" void kernel_launch(void* const* d_in, const int* in_sizes, int n_in,
                              void* d_out, int out_size, void* d_ws, size_t ws_size,
                              hipStream_t stream) {
  const float* x     = (const float*)d_in[0];
  const void*  mask  = d_in[1];
  const float* w_kvq = (const float*)d_in[2];
  const float* w_out = (const float*)d_in[3];

  float* out = (float*)d_out;                     // [BB, CC, TT]
  float* att = out + (long)BB * CC * TT;          // [HH*BB, TT, TT]

  char* wsb = (char*)d_ws;
  float*   maskf = (float*)(wsb + 0);             // 16 KB
  __bf16*  wkb   = (__bf16*)(wsb + 16384);        // 6 MB
  __bf16*  wob   = (__bf16*)(wsb + 6307840);      // 2 MB
  __bf16*  xT    = (__bf16*)(wsb + 8404992);      // 8 MB
  __bf16*  kqT   = (__bf16*)(wsb + 16793600);     // 16 MB [b][t][2C] (k | q)
  __bf16*  vbuf  = (__bf16*)(wsb + 33570816);     // 8 MB  [b][c][t]
  __bf16*  oT    = (__bf16*)(wsb + 41959424);     // 8 MB  [b][t][c]
  float2*  fst   = (float2*)(wsb + 50348032);     // 512 KB

  prep<<<2049, 256, 0, stream>>>(mask, maskf, w_kvq, w_out, wkb, wob);
  transpose_x<<<dim3(16, 16, BB), 256, 0, stream>>>(x, xT);
  // kvq GEMM: k/q -> kqT (transposed epilogue), v -> vbuf
  gemm_bt<0><<<dim3(8, 24, BB), 256, 0, stream>>>(
      wkb, xT, nullptr, nullptr, kqT, vbuf, (long)CC * TT);
  // online softmax stats -> fstats
  attn_fstats<<<dim3(16, HH * BB), 256, 0, stream>>>(kqT, maskf, fst);
  // recompute logits, write normalized att, o^T = p^T v^T
  gemm_pv<<<dim3(16, HH * BB), 256, 0, stream>>>(kqT, vbuf, fst, maskf, att, oT);
  // out = x + w_out · o
  gemm_bt<1><<<dim3(8, 8, BB), 256, 0, stream>>>(
      wob, oT, x, out, nullptr, nullptr, (long)CC * TT);
}